// Round 1
// baseline (151.255 us; speedup 1.0000x reference)
//
#include <hip/hip_runtime.h>
#include <hip/hip_bf16.h>

// CARNN fused kernel: 9-step RNN (D=64) + output projection to 300 actions.
// One block = 64 batch rows, 256 threads = 4 waves, each wave owns 16 rows.
// bf16 MFMA (16x16x32), f32 accumulate; hl round-trips through LDS each step.

#define BATCH   65536
#define SEQ     9
#define DMODEL  64
#define ANUM    300
#define BT      64
#define LSTR    72   // LDS row stride in bf16 elems (64 + 8 pad = 144 B/row)

typedef __attribute__((ext_vector_type(8))) short  bf16x8;  // 8 bf16 = 4 VGPRs
typedef __attribute__((ext_vector_type(4))) float  f32x4;

__device__ __forceinline__ unsigned short f2b(float f) {
    union { float f; unsigned int u; } x; x.f = f;
    unsigned int r = x.u + 0x7FFFu + ((x.u >> 16) & 1u);  // round-nearest-even
    return (unsigned short)(r >> 16);
}

__global__ __launch_bounds__(256, 4)
void carnn_kernel(const int*   __restrict__ acts,
                  const float* __restrict__ emb,
                  const float* __restrict__ Mw,
                  const float* __restrict__ Mb,
                  const float* __restrict__ Ww,
                  const float* __restrict__ Wb,
                  const float* __restrict__ outw,
                  const float* __restrict__ outb,
                  float*       __restrict__ out)
{
    __shared__ unsigned short Xl[BT * LSTR];
    __shared__ unsigned short Hl[BT * LSTR];
    __shared__ unsigned short Ml[DMODEL * LSTR];
    __shared__ unsigned short Wl[DMODEL * LSTR];

    const int tid   = threadIdx.x;
    const int bbase = blockIdx.x * BT;
    const int lane  = tid & 63;
    const int wv    = tid >> 6;        // wave 0..3
    const int lrow  = lane & 15;
    const int quad  = lane >> 4;
    const int m0    = wv * 16;         // this wave's row block

    // zero hl
    for (int i = tid; i < BT * LSTR; i += 256) Hl[i] = 0;

    // embedding-gather assignment: 4 threads per batch row
    const int grow = tid >> 2;         // 0..63
    const int gq   = tid & 3;

    for (int s = 0; s < SEQ; ++s) {
        // ---- stage M_s, W_s (64x64 f32 -> bf16 LDS), coalesced float4 ----
        const float* Ms = Mw + s * DMODEL * DMODEL;
        const float* Ws = Ww + s * DMODEL * DMODEL;
        #pragma unroll
        for (int i = 0; i < 4; ++i) {
            int e4 = tid + i * 256;          // float4 index 0..1023
            int e  = e4 << 2;
            int r  = e >> 6, c = e & 63;
            float4 vm = ((const float4*)Ms)[e4];
            float4 vw = ((const float4*)Ws)[e4];
            ushort4 um; um.x = f2b(vm.x); um.y = f2b(vm.y); um.z = f2b(vm.z); um.w = f2b(vm.w);
            ushort4 uw; uw.x = f2b(vw.x); uw.y = f2b(vw.y); uw.z = f2b(vw.z); uw.w = f2b(vw.w);
            *(ushort4*)&Ml[r * LSTR + c] = um;
            *(ushort4*)&Wl[r * LSTR + c] = uw;
        }
        // ---- gather X_s: emb_table[acts[b][s]] -> bf16 LDS ----
        {
            int id = acts[(bbase + grow) * SEQ + s];
            const float4* er = (const float4*)(emb + id * DMODEL);
            #pragma unroll
            for (int i = 0; i < 4; ++i) {
                int c4 = gq * 4 + i;         // float4 col index 0..15
                float4 v = er[c4];
                ushort4 u; u.x = f2b(v.x); u.y = f2b(v.y); u.z = f2b(v.z); u.w = f2b(v.w);
                *(ushort4*)&Xl[grow * LSTR + c4 * 4] = u;
            }
        }
        __syncthreads();

        // ---- A fragments: A[m=lane&15][k=quad*8+j], k-blocks {0,32} ----
        bf16x8 ax0 = *(const bf16x8*)&Xl[(m0 + lrow) * LSTR + quad * 8];
        bf16x8 ax1 = *(const bf16x8*)&Xl[(m0 + lrow) * LSTR + 32 + quad * 8];
        bf16x8 ah0 = *(const bf16x8*)&Hl[(m0 + lrow) * LSTR + quad * 8];
        bf16x8 ah1 = *(const bf16x8*)&Hl[(m0 + lrow) * LSTR + 32 + quad * 8];

        #pragma unroll
        for (int nt = 0; nt < 4; ++nt) {
            int nr = nt * 16 + lrow;     // B rows = output col, stored [n][k]
            bf16x8 bm0 = *(const bf16x8*)&Ml[nr * LSTR + quad * 8];
            bf16x8 bm1 = *(const bf16x8*)&Ml[nr * LSTR + 32 + quad * 8];
            bf16x8 bw0 = *(const bf16x8*)&Wl[nr * LSTR + quad * 8];
            bf16x8 bw1 = *(const bf16x8*)&Wl[nr * LSTR + 32 + quad * 8];
            f32x4 acc = {0.f, 0.f, 0.f, 0.f};
            acc = __builtin_amdgcn_mfma_f32_16x16x32_bf16(ax0, bm0, acc, 0, 0, 0);
            acc = __builtin_amdgcn_mfma_f32_16x16x32_bf16(ax1, bm1, acc, 0, 0, 0);
            acc = __builtin_amdgcn_mfma_f32_16x16x32_bf16(ah0, bw0, acc, 0, 0, 0);
            acc = __builtin_amdgcn_mfma_f32_16x16x32_bf16(ah1, bw1, acc, 0, 0, 0);

            int col = nt * 16 + lrow;
            float bias = Mb[s * DMODEL + col] + Wb[s * DMODEL + col];
            #pragma unroll
            for (int r = 0; r < 4; ++r) {
                float v = acc[r] + bias;
                float h = 1.f / (1.f + __expf(-v));
                // C/D layout: row = quad*4 + r (within wave's block), col = lrow-based
                Hl[(m0 + quad * 4 + r) * LSTR + col] = f2b(h);
            }
        }
        __syncthreads();  // protect M/W/X restage next iter; publish H
    }

    // ---- final projection: out[b][a] = hl[b] . outw[a] + outb[a] ----
    bf16x8 ah0 = *(const bf16x8*)&Hl[(m0 + lrow) * LSTR + quad * 8];
    bf16x8 ah1 = *(const bf16x8*)&Hl[(m0 + lrow) * LSTR + 32 + quad * 8];

    for (int cc = 0; cc < 5; ++cc) {     // chunks of 64 output cols (last: 44)
        #pragma unroll
        for (int i = 0; i < 4; ++i) {
            int e4 = tid + i * 256;
            int e  = e4 << 2;
            int r  = e >> 6, c = e & 63;
            int gr = cc * 64 + r;
            ushort4 u; u.x = 0; u.y = 0; u.z = 0; u.w = 0;
            if (gr < ANUM) {
                float4 v = ((const float4*)(outw + gr * DMODEL))[c >> 2];
                u.x = f2b(v.x); u.y = f2b(v.y); u.z = f2b(v.z); u.w = f2b(v.w);
            }
            *(ushort4*)&Ml[r * LSTR + c] = u;
        }
        __syncthreads();

        #pragma unroll
        for (int nt = 0; nt < 4; ++nt) {
            int nr = nt * 16 + lrow;
            bf16x8 b0 = *(const bf16x8*)&Ml[nr * LSTR + quad * 8];
            bf16x8 b1 = *(const bf16x8*)&Ml[nr * LSTR + 32 + quad * 8];
            f32x4 acc = {0.f, 0.f, 0.f, 0.f};
            acc = __builtin_amdgcn_mfma_f32_16x16x32_bf16(ah0, b0, acc, 0, 0, 0);
            acc = __builtin_amdgcn_mfma_f32_16x16x32_bf16(ah1, b1, acc, 0, 0, 0);

            int col = cc * 64 + nt * 16 + lrow;
            if (col < ANUM) {
                float bias = outb[col];
                int rowb = bbase + m0 + quad * 4;
                #pragma unroll
                for (int r = 0; r < 4; ++r)
                    out[(rowb + r) * ANUM + col] = acc[r] + bias;
            }
        }
        __syncthreads();  // before next chunk restages Ml
    }
}

extern "C" void kernel_launch(void* const* d_in, const int* in_sizes, int n_in,
                              void* d_out, int out_size, void* d_ws, size_t ws_size,
                              hipStream_t stream) {
    const int*   acts = (const int*)  d_in[0];
    const float* emb  = (const float*)d_in[1];
    const float* Mw   = (const float*)d_in[2];
    const float* Mb   = (const float*)d_in[3];
    const float* Ww   = (const float*)d_in[4];
    const float* Wb   = (const float*)d_in[5];
    const float* outw = (const float*)d_in[6];
    const float* outb = (const float*)d_in[7];
    float* out = (float*)d_out;
    (void)in_sizes; (void)n_in; (void)d_ws; (void)ws_size; (void)out_size;

    dim3 grid(BATCH / BT);
    dim3 block(256);
    carnn_kernel<<<grid, block, 0, stream>>>(acts, emb, Mw, Mb, Ww, Wb, outw, outb, out);
}

// Round 2
// 133.513 us; speedup vs baseline: 1.1329x; 1.1329x over previous
//
#include <hip/hip_runtime.h>
#include <hip/hip_bf16.h>

// CARNN: 9-step RNN (D=64) + projection to 300 actions, BATCH=65536.
// R2: pre-pass packs bf16 weights in MFMA B-fragment order into d_ws;
// main kernel is BARRIER-FREE (hl is wave-private; B-frags direct from L2).

#define BATCH   65536
#define SEQ     9
#define DMODEL  64
#define ANUM    300
#define BT      64
#define LSTR    72   // Hl row stride (bf16 elems), 144 B -> 16B-aligned rows

// ws layout (bf16 element offsets)
#define WS_M    0        // 9*4096 = 36864   M fragments [s][nt][kb][lane][8]
#define WS_W    36864    // 36864            W fragments
#define WS_OW   73728    // 5*4096 = 20480   outw fragments [cc][nt][kb][lane][8]
#define WS_EMB  94208    // 301*64 = 19264   bf16 emb table (natural layout)
#define WS_END  113472
#define WS_BSUM_BYTES (WS_END * 2)   // 226944; then 576 floats (Mb+Wb)

typedef __attribute__((ext_vector_type(8))) short  bf16x8;
typedef __attribute__((ext_vector_type(4))) float  f32x4;

__device__ __forceinline__ unsigned short f2b(float f) {
    union { float f; unsigned int u; } x; x.f = f;
    unsigned int r = x.u + 0x7FFFu + ((x.u >> 16) & 1u);
    return (unsigned short)(r >> 16);
}

// ---------------- pre-pass: convert + pack ----------------
#define PP_TOTAL (36864 + 20480 + 19264 + 576)

__global__ void prepack(const float* __restrict__ Mw, const float* __restrict__ Ww,
                        const float* __restrict__ outw, const float* __restrict__ emb,
                        const float* __restrict__ Mb, const float* __restrict__ Wb,
                        unsigned short* __restrict__ wsb, float* __restrict__ bsum)
{
    int t = blockIdx.x * 256 + threadIdx.x;
    if (t < 36864) {
        // M + W fragments: t = s*4096 + nt*1024 + kb*512 + lane*8 + j
        int j    = t & 7;
        int lane = (t >> 3) & 63;
        int kb   = (t >> 9) & 1;
        int nt   = (t >> 10) & 3;
        int s    = t >> 12;
        int nr   = nt * 16 + (lane & 15);
        int k    = kb * 32 + ((lane >> 4) << 3) + j;
        wsb[WS_M + t] = f2b(Mw[(s * DMODEL + nr) * DMODEL + k]);
        wsb[WS_W + t] = f2b(Ww[(s * DMODEL + nr) * DMODEL + k]);
        return;
    }
    t -= 36864;
    if (t < 20480) {
        int j    = t & 7;
        int lane = (t >> 3) & 63;
        int kb   = (t >> 9) & 1;
        int nt   = (t >> 10) & 3;
        int cc   = t >> 12;
        int col  = cc * 64 + nt * 16 + (lane & 15);
        int k    = kb * 32 + ((lane >> 4) << 3) + j;
        float v  = (col < ANUM) ? outw[col * DMODEL + k] : 0.f;
        wsb[WS_OW + t] = f2b(v);
        return;
    }
    t -= 20480;
    if (t < 19264) {
        wsb[WS_EMB + t] = f2b(emb[t]);
        return;
    }
    t -= 19264;
    if (t < 576) {
        bsum[t] = Mb[t] + Wb[t];
    }
}

// ---------------- main: barrier-free fused RNN ----------------
__global__ __launch_bounds__(256, 4)
void carnn_main(const int* __restrict__ acts,
                const unsigned short* __restrict__ wsb,
                const float* __restrict__ bsum,
                const float* __restrict__ outb,
                float* __restrict__ out)
{
    __shared__ unsigned short Hl[BT * LSTR];

    const int tid  = threadIdx.x;
    const int lane = tid & 63;
    const int wv   = tid >> 6;
    const int lrow = lane & 15;
    const int quad = lane >> 4;
    const int m0   = wv * 16;                  // wave's private 16-row block

    const int brow = blockIdx.x * BT + m0 + lrow;  // A-row batch index
    const int row9 = brow * SEQ;

    // zero this wave's Hl region (wave-private; no barrier needed)
    for (int i = lane; i < 16 * LSTR; i += 64) Hl[m0 * LSTR + i] = 0;

    const unsigned short* Mp = wsb + WS_M;
    const unsigned short* Wp = wsb + WS_W;
    const unsigned short* Op = wsb + WS_OW;
    const unsigned short* Eb = wsb + WS_EMB;

    for (int s = 0; s < SEQ; ++s) {
        int id = acts[row9 + s];
        const bf16x8* ex = (const bf16x8*)(Eb + id * DMODEL);
        bf16x8 ax0 = ex[quad];          // X[m=lrow][k=quad*8..]
        bf16x8 ax1 = ex[4 + quad];      // k = 32 + quad*8
        bf16x8 ah0 = *(const bf16x8*)&Hl[(m0 + lrow) * LSTR + quad * 8];
        bf16x8 ah1 = *(const bf16x8*)&Hl[(m0 + lrow) * LSTR + 32 + quad * 8];

        #pragma unroll
        for (int nt = 0; nt < 4; ++nt) {
            const int fo = (s * 4 + nt) * 1024 + lane * 8;
            bf16x8 bm0 = *(const bf16x8*)&Mp[fo];
            bf16x8 bm1 = *(const bf16x8*)&Mp[fo + 512];
            bf16x8 bw0 = *(const bf16x8*)&Wp[fo];
            bf16x8 bw1 = *(const bf16x8*)&Wp[fo + 512];
            f32x4 acc = {0.f, 0.f, 0.f, 0.f};
            acc = __builtin_amdgcn_mfma_f32_16x16x32_bf16(ax0, bm0, acc, 0, 0, 0);
            acc = __builtin_amdgcn_mfma_f32_16x16x32_bf16(ax1, bm1, acc, 0, 0, 0);
            acc = __builtin_amdgcn_mfma_f32_16x16x32_bf16(ah0, bw0, acc, 0, 0, 0);
            acc = __builtin_amdgcn_mfma_f32_16x16x32_bf16(ah1, bw1, acc, 0, 0, 0);

            const int col  = nt * 16 + lrow;
            const float bias = bsum[s * DMODEL + col];
            #pragma unroll
            for (int r = 0; r < 4; ++r) {
                float v = acc[r] + bias;
                float h = 1.f / (1.f + __expf(-v));
                Hl[(m0 + quad * 4 + r) * LSTR + col] = f2b(h);
            }
        }
        // no __syncthreads: Hl region is wave-private, DS ops in-order per wave
    }

    // ---- projection: out = hl @ outw^T + outb ----
    bf16x8 ah0 = *(const bf16x8*)&Hl[(m0 + lrow) * LSTR + quad * 8];
    bf16x8 ah1 = *(const bf16x8*)&Hl[(m0 + lrow) * LSTR + 32 + quad * 8];
    const int rowb = blockIdx.x * BT + m0 + quad * 4;

    #pragma unroll
    for (int cc = 0; cc < 5; ++cc) {
        #pragma unroll
        for (int nt = 0; nt < 4; ++nt) {
            const int fo = (cc * 4 + nt) * 1024 + lane * 8;
            bf16x8 b0 = *(const bf16x8*)&Op[fo];
            bf16x8 b1 = *(const bf16x8*)&Op[fo + 512];
            f32x4 acc = {0.f, 0.f, 0.f, 0.f};
            acc = __builtin_amdgcn_mfma_f32_16x16x32_bf16(ah0, b0, acc, 0, 0, 0);
            acc = __builtin_amdgcn_mfma_f32_16x16x32_bf16(ah1, b1, acc, 0, 0, 0);

            const int col = cc * 64 + nt * 16 + lrow;
            if (col < ANUM) {
                const float bias = outb[col];
                #pragma unroll
                for (int r = 0; r < 4; ++r)
                    out[(rowb + r) * ANUM + col] = acc[r] + bias;
            }
        }
    }
}

extern "C" void kernel_launch(void* const* d_in, const int* in_sizes, int n_in,
                              void* d_out, int out_size, void* d_ws, size_t ws_size,
                              hipStream_t stream) {
    const int*   acts = (const int*)  d_in[0];
    const float* emb  = (const float*)d_in[1];
    const float* Mw   = (const float*)d_in[2];
    const float* Mb   = (const float*)d_in[3];
    const float* Ww   = (const float*)d_in[4];
    const float* Wb   = (const float*)d_in[5];
    const float* outw = (const float*)d_in[6];
    const float* outb = (const float*)d_in[7];
    float* out = (float*)d_out;
    (void)in_sizes; (void)n_in; (void)ws_size; (void)out_size;

    unsigned short* wsb = (unsigned short*)d_ws;
    float* bsum = (float*)((char*)d_ws + WS_BSUM_BYTES);

    prepack<<<(PP_TOTAL + 255) / 256, 256, 0, stream>>>(Mw, Ww, outw, emb, Mb, Wb, wsb, bsum);
    carnn_main<<<BATCH / BT, 256, 0, stream>>>(acts, wsb, bsum, outb, out);
}